// Round 10
// baseline (69.029 us; speedup 1.0000x reference)
//
#include <hip/hip_runtime.h>

#define KDIM 32
#define EPSC 1e-6f
#define NEG_BIG (-1e30f)

// ============ K1: gather + inline softmax -> per-block partial M/S (plain stores) ============
__global__ __launch_bounds__(1024) void reduce_M(
    const float* __restrict__ Z_i, const float* __restrict__ Z_j,
    const float* __restrict__ Gate,
    const int* __restrict__ si, const int* __restrict__ sj,
    float* __restrict__ Mpart, float* __restrict__ Spart,
    int n_i, int n_j, int m_i, int m)
{
    __shared__ float Zl[32][33], Gl[32][33];
    __shared__ float cmax[32], cinv[32];
    __shared__ int nodeL[32];
    int q = threadIdx.x, p = threadIdx.y;
    int m0 = blockIdx.x * 32;
    if (p == 0) {
        int mi = m0 + q;
        nodeL[q] = (mi < m) ? ((mi < m_i) ? si[mi] : sj[mi - m_i]) : -1;
    }
    __syncthreads();
    int nq = nodeL[q];
    float zv = 0.f;
    if (nq >= 0) {
        int mi = m0 + q;
        const float* Zr = (mi < m_i) ? Z_i : Z_j;
        int n = (mi < m_i) ? n_i : n_j;
        zv = Zr[p * n + nq];
    }
    Zl[p][q] = zv;
    __syncthreads();
    if (p == 0) {
        float mx = -1e30f;
        #pragma unroll
        for (int r = 0; r < 32; r++) mx = fmaxf(mx, Zl[r][q]);
        float s = 0.f;
        #pragma unroll
        for (int r = 0; r < 32; r++) s += __expf(Zl[r][q] - mx);
        cmax[q] = mx; cinv[q] = 1.f / s;
    }
    __syncthreads();
    float zs = (nq >= 0) ? __expf(Zl[p][q] - cmax[q]) * cinv[q] : 0.f;
    Zl[p][q] = zs;          // own-cell overwrite; raw values consumed above
    __syncthreads();
    int np_ = nodeL[p];
    float gv = 0.f;
    if (np_ >= 0) {
        float g = 1.f / (1.f + __expf(-Gate[(size_t)np_ * KDIM + q]));
        gv = Zl[q][p] * g;   // raw node id for Gate — faithful to reference
    }
    Gl[p][q] = gv;
    __syncthreads();
    float acc = 0.f;
    #pragma unroll
    for (int s = 0; s < 32; s++) acc = fmaf(Zl[p][s], Gl[s][q], acc);
    Mpart[(size_t)blockIdx.x * 1024 + p * 32 + q] = acc;
    if (p == 0) {
        float ss = 0.f;
        #pragma unroll
        for (int s = 0; s < 32; s++) ss += Gl[s][q];
        Spart[(size_t)blockIdx.x * 32 + q] = ss;
    }
}

// ============ K2: fused partial-reduce (8-way MLP) + AZC = A @ (M/s) — one block ============
__global__ __launch_bounds__(1024) void azc_fused(
    const float* __restrict__ Mpart, const float* __restrict__ Spart, int nblkA,
    const float* __restrict__ A, float* __restrict__ AZC)
{
    __shared__ float Cn[32][33];
    __shared__ float Ssum[32];
    int q = threadIdx.x, p = threadIdx.y;
    int idx = p * 32 + q;
    // 8 independent accumulators -> 8 loads in flight (in-order GCN needs explicit MLP)
    float a0 = 0.f, a1 = 0.f, a2 = 0.f, a3 = 0.f, a4 = 0.f, a5 = 0.f, a6 = 0.f, a7 = 0.f;
    int b = 0;
    for (; b + 8 <= nblkA; b += 8) {
        a0 += Mpart[(size_t)(b + 0) * 1024 + idx];
        a1 += Mpart[(size_t)(b + 1) * 1024 + idx];
        a2 += Mpart[(size_t)(b + 2) * 1024 + idx];
        a3 += Mpart[(size_t)(b + 3) * 1024 + idx];
        a4 += Mpart[(size_t)(b + 4) * 1024 + idx];
        a5 += Mpart[(size_t)(b + 5) * 1024 + idx];
        a6 += Mpart[(size_t)(b + 6) * 1024 + idx];
        a7 += Mpart[(size_t)(b + 7) * 1024 + idx];
    }
    for (; b < nblkA; b++) a0 += Mpart[(size_t)b * 1024 + idx];
    float macc = ((a0 + a1) + (a2 + a3)) + ((a4 + a5) + (a6 + a7));
    if (p == 0) {
        float s0 = 0.f, s1 = 0.f, s2 = 0.f, s3 = 0.f;
        int c = 0;
        for (; c + 4 <= nblkA; c += 4) {
            s0 += Spart[(size_t)(c + 0) * 32 + q];
            s1 += Spart[(size_t)(c + 1) * 32 + q];
            s2 += Spart[(size_t)(c + 2) * 32 + q];
            s3 += Spart[(size_t)(c + 3) * 32 + q];
        }
        for (; c < nblkA; c++) s0 += Spart[(size_t)c * 32 + q];
        Ssum[q] = 1.f / ((s0 + s1) + (s2 + s3));
    }
    __syncthreads();
    Cn[p][q] = macc * Ssum[q];
    __syncthreads();
    float s = 0.f;
    #pragma unroll
    for (int j = 0; j < 32; j++) s = fmaf(A[p * 32 + j], Cn[j][q], s);
    AZC[p * 32 + q] = s;
}

// ============ K3: X + norms; Xj stored pre-shifted by -EPSC ============
__global__ __launch_bounds__(256) void xall(
    const float* __restrict__ AZC,
    const float* __restrict__ Z_i, const float* __restrict__ Z_j,
    float* __restrict__ Xi_all, float* __restrict__ Xj_all,
    float* __restrict__ normI, float* __restrict__ normJ, int n_i, int n_j)
{
    int node = blockIdx.x * 256 + threadIdx.x;
    int nTot = n_i + n_j;
    if (node >= nTot) return;
    const float* Zr; float* X; float* Np; int n, c; float shift;
    if (node < n_i) { Zr = Z_i; X = Xi_all; Np = normI; n = n_i; c = node; shift = 0.f; }
    else            { Zr = Z_j; X = Xj_all; Np = normJ; n = n_j; c = node - n_i; shift = EPSC; }
    float z[32]; float mx = -1e30f;
    #pragma unroll
    for (int p = 0; p < 32; p++) { z[p] = Zr[p * n + c]; mx = fmaxf(mx, z[p]); }
    float ssum = 0.f;
    #pragma unroll
    for (int p = 0; p < 32; p++) { z[p] = __expf(z[p] - mx); ssum += z[p]; }
    float inv = 1.f / ssum;
    #pragma unroll
    for (int p = 0; p < 32; p++) z[p] *= inv;
    float nrm = 0.f;
    #pragma unroll
    for (int d0 = 0; d0 < 8; d0++) {
        float xs[4];
        #pragma unroll
        for (int r = 0; r < 4; r++) {
            int dd = d0 * 4 + r;
            float x = 0.f;
            #pragma unroll
            for (int p = 0; p < 32; p++) x = fmaf(AZC[dd * 32 + p], z[p], x);
            x -= shift;                 // y_j = x_j - eps; x_i unchanged
            nrm = fmaf(x, x, nrm);
            xs[r] = x;
        }
        ((float4*)(X + (size_t)c * 32))[d0] = make_float4(xs[0], xs[1], xs[2], xs[3]);
    }
    Np[c] = nrm;
}

// ============ K4: pairwise (Gram 128x128, 8x8/thread) + edge blocks ============
__global__ __launch_bounds__(256) void pair_edge(
    const float* __restrict__ Xi_all, const float* __restrict__ Xj_all,
    const float* __restrict__ normI, const float* __restrict__ normJ,
    const int* __restrict__ si, const int* __restrict__ sj,
    const int* __restrict__ sei, const int* __restrict__ sej,
    const float* __restrict__ beta, const float* __restrict__ gamma,
    int m_i, int m_j, int E, int nbi, int nbj, float* __restrict__ slots)
{
    __shared__ float XiL[128][36], XjL[128][36];   // 36: 144B rows, 16B-aligned
    __shared__ float an[128], bn[128], bel[128], gal[128];
    __shared__ float wsum[4];
    int bid = blockIdx.x, tid = threadIdx.x;
    int npair = nbi * nbj;
    float part = 0.f;

    if (bid < npair) {
        int i0 = (bid / nbj) * 128, j0 = (bid % nbj) * 128;
        if (tid < 128) {
            int gi = i0 + tid;
            if (gi < m_i) { int nd = si[gi]; an[tid] = normI[nd]; bel[tid] = beta[nd]; }
            else          { an[tid] = 0.f;  bel[tid] = NEG_BIG; }
        } else {
            int r = tid - 128, gj = j0 + r;
            if (gj < m_j) { int nd = sj[gj]; bn[r] = normJ[nd]; gal[r] = gamma[nd]; }
            else          { bn[r] = 0.f;  gal[r] = NEG_BIG; }
        }
        #pragma unroll
        for (int l = 0; l < 4; l++) {
            int slot = tid + l * 256;
            int row = slot >> 3, d4 = slot & 7;
            int gi = i0 + row;
            float4 v = make_float4(0.f, 0.f, 0.f, 0.f);
            if (gi < m_i) v = ((const float4*)(Xi_all + (size_t)si[gi] * 32))[d4];
            *(float4*)&XiL[row][d4 * 4] = v;
            int gj = j0 + row;
            float4 w = make_float4(0.f, 0.f, 0.f, 0.f);
            if (gj < m_j) w = ((const float4*)(Xj_all + (size_t)sj[gj] * 32))[d4];
            *(float4*)&XjL[row][d4 * 4] = w;
        }
        __syncthreads();
        int ti = tid & 15, tj = tid >> 4;
        float dot[8][8] = {};
        #pragma unroll
        for (int d4 = 0; d4 < 8; d4++) {
            float4 av[8], bv[8];
            #pragma unroll
            for (int r = 0; r < 8; r++) av[r] = *(const float4*)&XiL[ti + 16 * r][d4 * 4];
            #pragma unroll
            for (int c = 0; c < 8; c++) bv[c] = *(const float4*)&XjL[tj + 16 * c][d4 * 4];
            #pragma unroll
            for (int r = 0; r < 8; r++) {
                #pragma unroll
                for (int c = 0; c < 8; c++) {
                    dot[r][c] = fmaf(av[r].x, bv[c].x, dot[r][c]);
                    dot[r][c] = fmaf(av[r].y, bv[c].y, dot[r][c]);
                    dot[r][c] = fmaf(av[r].z, bv[c].z, dot[r][c]);
                    dot[r][c] = fmaf(av[r].w, bv[c].w, dot[r][c]);
                }
            }
        }
        float lp = 0.f;
        #pragma unroll
        for (int r = 0; r < 8; r++) {
            float ar = an[ti + 16 * r], br = bel[ti + 16 * r];
            #pragma unroll
            for (int c = 0; c < 8; c++) {
                float d2 = fmaf(-2.f, dot[r][c], ar + bn[tj + 16 * c]);
                float dist = sqrtf(fmaxf(d2, 0.f));
                lp += __expf(br + gal[tj + 16 * c] - dist);
            }
        }
        part = -lp;
    } else {
        int e = (bid - npair) * 256 + tid;
        if (e < E) {
            int a = sei[e], b = sej[e];
            const float4* xa = (const float4*)(Xi_all + (size_t)a * 32);
            const float4* xb = (const float4*)(Xj_all + (size_t)b * 32);  // pre-shifted
            float s = 0.f;
            #pragma unroll
            for (int qq = 0; qq < 8; qq++) {
                float4 va = xa[qq], vb = xb[qq];
                float t0;
                t0 = va.x - vb.x; s = fmaf(t0, t0, s);
                t0 = va.y - vb.y; s = fmaf(t0, t0, s);
                t0 = va.z - vb.z; s = fmaf(t0, t0, s);
                t0 = va.w - vb.w; s = fmaf(t0, t0, s);
            }
            part = beta[a] + gamma[b] - sqrtf(s);
        }
    }

    #pragma unroll
    for (int o = 32; o > 0; o >>= 1) part += __shfl_down(part, o, 64);
    if ((tid & 63) == 0) wsum[tid >> 6] = part;
    __syncthreads();
    if (tid == 0) slots[bid] = wsum[0] + wsum[1] + wsum[2] + wsum[3];
}

// ============ K5: final reduce ============
__global__ __launch_bounds__(256) void final_reduce(
    const float* __restrict__ slots, int n, float* __restrict__ out)
{
    __shared__ float w[4];
    int tid = threadIdx.x;
    float v = 0.f;
    for (int i = tid; i < n; i += 256) v += slots[i];
    #pragma unroll
    for (int o = 32; o > 0; o >>= 1) v += __shfl_down(v, o, 64);
    if ((tid & 63) == 0) w[tid >> 6] = v;
    __syncthreads();
    if (tid == 0) out[0] = w[0] + w[1] + w[2] + w[3];
}

extern "C" void kernel_launch(void* const* d_in, const int* in_sizes, int n_in,
                              void* d_out, int out_size, void* d_ws, size_t ws_size,
                              hipStream_t stream) {
    const float* beta  = (const float*)d_in[0];
    const float* gamma = (const float*)d_in[1];
    const float* Amat  = (const float*)d_in[2];
    const float* Z_i   = (const float*)d_in[3];
    const float* Z_j   = (const float*)d_in[4];
    const float* Gate  = (const float*)d_in[5];
    const int*   si    = (const int*)d_in[6];
    const int*   sj    = (const int*)d_in[7];
    const int*   sei   = (const int*)d_in[8];
    const int*   sej   = (const int*)d_in[9];

    int n_i = in_sizes[0], n_j = in_sizes[1];
    int m_i = in_sizes[6], m_j = in_sizes[7], E = in_sizes[8];
    int m = m_i + m_j;
    int nTot = n_i + n_j;
    int nblkA = (m + 31) / 32;

    float* ws = (float*)d_ws;
    float* Mpart  = ws; ws += (size_t)nblkA * 1024;
    float* Spart  = ws; ws += (size_t)nblkA * 32;
    float* AZC    = ws; ws += 1024;
    float* slots  = ws; ws += 4096;
    float* normI  = ws; ws += n_i;
    float* normJ  = ws; ws += n_j;
    float* Xi_all = ws; ws += (size_t)n_i * KDIM;
    float* Xj_all = ws; ws += (size_t)n_j * KDIM;

    reduce_M<<<nblkA, dim3(32, 32), 0, stream>>>(
        Z_i, Z_j, Gate, si, sj, Mpart, Spart, n_i, n_j, m_i, m);

    azc_fused<<<1, dim3(32, 32), 0, stream>>>(Mpart, Spart, nblkA, Amat, AZC);

    xall<<<(nTot + 255) / 256, 256, 0, stream>>>(AZC, Z_i, Z_j, Xi_all, Xj_all,
                                                 normI, normJ, n_i, n_j);

    int nbi = (m_i + 127) / 128, nbj = (m_j + 127) / 128;
    int nedge = (E + 255) / 256;
    int nblkTot = nbi * nbj + nedge;
    pair_edge<<<nblkTot, 256, 0, stream>>>(
        Xi_all, Xj_all, normI, normJ, si, sj, sei, sej, beta, gamma,
        m_i, m_j, E, nbi, nbj, slots);

    final_reduce<<<1, 256, 0, stream>>>(slots, nblkTot, (float*)d_out);
}

// Round 11
// 53.926 us; speedup vs baseline: 1.2801x; 1.2801x over previous
//
#include <hip/hip_runtime.h>

#define KDIM 32
#define EPSC 1e-6f
#define NEG_BIG (-1e30f)
#define NGRP 16

// ============ K1: gather + inline softmax -> per-block partial M/S (no atomics) ============
__global__ __launch_bounds__(1024) void reduce_M(
    const float* __restrict__ Z_i, const float* __restrict__ Z_j,
    const float* __restrict__ Gate,
    const int* __restrict__ si, const int* __restrict__ sj,
    float* __restrict__ Mpart, float* __restrict__ Spart,
    int n_i, int n_j, int m_i, int m)
{
    __shared__ float Zl[32][33], Gl[32][33];
    __shared__ float cmax[32], cinv[32];
    __shared__ int nodeL[32];
    int q = threadIdx.x, p = threadIdx.y;
    int m0 = blockIdx.x * 32;
    if (p == 0) {
        int mi = m0 + q;
        nodeL[q] = (mi < m) ? ((mi < m_i) ? si[mi] : sj[mi - m_i]) : -1;
    }
    __syncthreads();
    int nq = nodeL[q];
    float zv = 0.f;
    if (nq >= 0) {
        int mi = m0 + q;
        const float* Zr = (mi < m_i) ? Z_i : Z_j;
        int n = (mi < m_i) ? n_i : n_j;
        zv = Zr[p * n + nq];
    }
    Zl[p][q] = zv;
    __syncthreads();
    if (p == 0) {
        float mx = -1e30f;
        #pragma unroll
        for (int r = 0; r < 32; r++) mx = fmaxf(mx, Zl[r][q]);
        float s = 0.f;
        #pragma unroll
        for (int r = 0; r < 32; r++) s += __expf(Zl[r][q] - mx);
        cmax[q] = mx; cinv[q] = 1.f / s;
    }
    __syncthreads();
    float zs = (nq >= 0) ? __expf(Zl[p][q] - cmax[q]) * cinv[q] : 0.f;
    Zl[p][q] = zs;          // own-cell overwrite; raw values consumed above
    __syncthreads();
    int np_ = nodeL[p];
    float gv = 0.f;
    if (np_ >= 0) {
        float g = 1.f / (1.f + __expf(-Gate[(size_t)np_ * KDIM + q]));
        gv = Zl[q][p] * g;   // raw node id for Gate — faithful to reference
    }
    Gl[p][q] = gv;
    __syncthreads();
    float acc = 0.f;
    #pragma unroll
    for (int s = 0; s < 32; s++) acc = fmaf(Zl[p][s], Gl[s][q], acc);
    Mpart[(size_t)blockIdx.x * 1024 + p * 32 + q] = acc;
    if (p == 0) {
        float ss = 0.f;
        #pragma unroll
        for (int s = 0; s < 32; s++) ss += Gl[s][q];
        Spart[(size_t)blockIdx.x * 32 + q] = ss;
    }
}

// ============ K1b: tree-reduce 157 partials -> 16 partials (coalesced, parallel) ============
__global__ __launch_bounds__(1024) void reduce2(
    const float* __restrict__ Mpart, const float* __restrict__ Spart, int nblkA,
    float* __restrict__ Mpart2, float* __restrict__ Spart2)
{
    int g = blockIdx.x;           // 0..NGRP-1
    int idx = threadIdx.x;        // 0..1023
    float s = 0.f;
    for (int b = g; b < nblkA; b += NGRP)
        s += Mpart[(size_t)b * 1024 + idx];
    Mpart2[g * 1024 + idx] = s;
    if (idx < 32) {
        float ss = 0.f;
        for (int b = g; b < nblkA; b += NGRP)
            ss += Spart[(size_t)b * 32 + idx];
        Spart2[g * 32 + idx] = ss;
    }
}

// ============ K2a: AZC = A @ (M / s) ============
__global__ __launch_bounds__(1024) void azc_kernel(
    const float* __restrict__ Mpart2, const float* __restrict__ Spart2,
    const float* __restrict__ A, float* __restrict__ AZC)
{
    __shared__ float Cn[32][33];
    __shared__ float Ssum[32];
    int q = threadIdx.x, p = threadIdx.y;
    int idx = p * 32 + q;
    float macc = 0.f;
    #pragma unroll
    for (int g = 0; g < NGRP; g++) macc += Mpart2[g * 1024 + idx];
    if (p == 0) {
        float ss = 0.f;
        #pragma unroll
        for (int g = 0; g < NGRP; g++) ss += Spart2[g * 32 + q];
        Ssum[q] = 1.f / ss;
    }
    __syncthreads();
    Cn[p][q] = macc * Ssum[q];
    __syncthreads();
    float s = 0.f;
    #pragma unroll
    for (int j = 0; j < 32; j++) s = fmaf(A[p * 32 + j], Cn[j][q], s);
    AZC[p * 32 + q] = s;
}

// ============ K2b: X + norms; Xj stored pre-shifted by -EPSC ============
__global__ __launch_bounds__(256) void xall(
    const float* __restrict__ AZC,
    const float* __restrict__ Z_i, const float* __restrict__ Z_j,
    float* __restrict__ Xi_all, float* __restrict__ Xj_all,
    float* __restrict__ normI, float* __restrict__ normJ, int n_i, int n_j)
{
    int node = blockIdx.x * 256 + threadIdx.x;
    int nTot = n_i + n_j;
    if (node >= nTot) return;
    const float* Zr; float* X; float* Np; int n, c; float shift;
    if (node < n_i) { Zr = Z_i; X = Xi_all; Np = normI; n = n_i; c = node; shift = 0.f; }
    else            { Zr = Z_j; X = Xj_all; Np = normJ; n = n_j; c = node - n_i; shift = EPSC; }
    float z[32]; float mx = -1e30f;
    #pragma unroll
    for (int p = 0; p < 32; p++) { z[p] = Zr[p * n + c]; mx = fmaxf(mx, z[p]); }
    float ssum = 0.f;
    #pragma unroll
    for (int p = 0; p < 32; p++) { z[p] = __expf(z[p] - mx); ssum += z[p]; }
    float inv = 1.f / ssum;
    #pragma unroll
    for (int p = 0; p < 32; p++) z[p] *= inv;
    float nrm = 0.f;
    #pragma unroll
    for (int d0 = 0; d0 < 8; d0++) {
        float xs[4];
        #pragma unroll
        for (int r = 0; r < 4; r++) {
            int dd = d0 * 4 + r;
            float x = 0.f;
            #pragma unroll
            for (int p = 0; p < 32; p++) x = fmaf(AZC[dd * 32 + p], z[p], x);
            x -= shift;                 // y_j = x_j - eps; x_i unchanged
            nrm = fmaf(x, x, nrm);
            xs[r] = x;
        }
        ((float4*)(X + (size_t)c * 32))[d0] = make_float4(xs[0], xs[1], xs[2], xs[3]);
    }
    Np[c] = nrm;
}

// ============ K3: pairwise (Gram 128x128, 8x8/thread) + edge blocks ============
__global__ __launch_bounds__(256) void pair_edge(
    const float* __restrict__ Xi_all, const float* __restrict__ Xj_all,
    const float* __restrict__ normI, const float* __restrict__ normJ,
    const int* __restrict__ si, const int* __restrict__ sj,
    const int* __restrict__ sei, const int* __restrict__ sej,
    const float* __restrict__ beta, const float* __restrict__ gamma,
    int m_i, int m_j, int E, int nbi, int nbj, float* __restrict__ slots)
{
    __shared__ float XiL[128][36], XjL[128][36];   // 36: 144B rows, 16B-aligned
    __shared__ float an[128], bn[128], bel[128], gal[128];
    __shared__ float wsum[4];
    int bid = blockIdx.x, tid = threadIdx.x;
    int npair = nbi * nbj;
    float part = 0.f;

    if (bid < npair) {
        int i0 = (bid / nbj) * 128, j0 = (bid % nbj) * 128;
        if (tid < 128) {
            int gi = i0 + tid;
            if (gi < m_i) { int nd = si[gi]; an[tid] = normI[nd]; bel[tid] = beta[nd]; }
            else          { an[tid] = 0.f;  bel[tid] = NEG_BIG; }
        } else {
            int r = tid - 128, gj = j0 + r;
            if (gj < m_j) { int nd = sj[gj]; bn[r] = normJ[nd]; gal[r] = gamma[nd]; }
            else          { bn[r] = 0.f;  gal[r] = NEG_BIG; }
        }
        #pragma unroll
        for (int l = 0; l < 4; l++) {
            int slot = tid + l * 256;
            int row = slot >> 3, d4 = slot & 7;
            int gi = i0 + row;
            float4 v = make_float4(0.f, 0.f, 0.f, 0.f);
            if (gi < m_i) v = ((const float4*)(Xi_all + (size_t)si[gi] * 32))[d4];
            *(float4*)&XiL[row][d4 * 4] = v;
            int gj = j0 + row;
            float4 w = make_float4(0.f, 0.f, 0.f, 0.f);
            if (gj < m_j) w = ((const float4*)(Xj_all + (size_t)sj[gj] * 32))[d4];
            *(float4*)&XjL[row][d4 * 4] = w;
        }
        __syncthreads();
        int ti = tid & 15, tj = tid >> 4;
        float dot[8][8] = {};
        #pragma unroll
        for (int d4 = 0; d4 < 8; d4++) {
            float4 av[8], bv[8];
            #pragma unroll
            for (int r = 0; r < 8; r++) av[r] = *(const float4*)&XiL[ti + 16 * r][d4 * 4];
            #pragma unroll
            for (int c = 0; c < 8; c++) bv[c] = *(const float4*)&XjL[tj + 16 * c][d4 * 4];
            #pragma unroll
            for (int r = 0; r < 8; r++) {
                #pragma unroll
                for (int c = 0; c < 8; c++) {
                    dot[r][c] = fmaf(av[r].x, bv[c].x, dot[r][c]);
                    dot[r][c] = fmaf(av[r].y, bv[c].y, dot[r][c]);
                    dot[r][c] = fmaf(av[r].z, bv[c].z, dot[r][c]);
                    dot[r][c] = fmaf(av[r].w, bv[c].w, dot[r][c]);
                }
            }
        }
        float lp = 0.f;
        #pragma unroll
        for (int r = 0; r < 8; r++) {
            float ar = an[ti + 16 * r], br = bel[ti + 16 * r];
            #pragma unroll
            for (int c = 0; c < 8; c++) {
                float d2 = fmaf(-2.f, dot[r][c], ar + bn[tj + 16 * c]);
                float dist = sqrtf(fmaxf(d2, 0.f));
                lp += __expf(br + gal[tj + 16 * c] - dist);
            }
        }
        part = -lp;
    } else {
        int e = (bid - npair) * 256 + tid;
        if (e < E) {
            int a = sei[e], b = sej[e];
            const float4* xa = (const float4*)(Xi_all + (size_t)a * 32);
            const float4* xb = (const float4*)(Xj_all + (size_t)b * 32);  // pre-shifted
            float s = 0.f;
            #pragma unroll
            for (int qq = 0; qq < 8; qq++) {
                float4 va = xa[qq], vb = xb[qq];
                float t0;
                t0 = va.x - vb.x; s = fmaf(t0, t0, s);
                t0 = va.y - vb.y; s = fmaf(t0, t0, s);
                t0 = va.z - vb.z; s = fmaf(t0, t0, s);
                t0 = va.w - vb.w; s = fmaf(t0, t0, s);
            }
            part = beta[a] + gamma[b] - sqrtf(s);
        }
    }

    #pragma unroll
    for (int o = 32; o > 0; o >>= 1) part += __shfl_down(part, o, 64);
    if ((tid & 63) == 0) wsum[tid >> 6] = part;
    __syncthreads();
    if (tid == 0) slots[bid] = wsum[0] + wsum[1] + wsum[2] + wsum[3];
}

// ============ K4: final reduce ============
__global__ __launch_bounds__(256) void final_reduce(
    const float* __restrict__ slots, int n, float* __restrict__ out)
{
    __shared__ float w[4];
    int tid = threadIdx.x;
    float v = 0.f;
    for (int i = tid; i < n; i += 256) v += slots[i];
    #pragma unroll
    for (int o = 32; o > 0; o >>= 1) v += __shfl_down(v, o, 64);
    if ((tid & 63) == 0) w[tid >> 6] = v;
    __syncthreads();
    if (tid == 0) out[0] = w[0] + w[1] + w[2] + w[3];
}

extern "C" void kernel_launch(void* const* d_in, const int* in_sizes, int n_in,
                              void* d_out, int out_size, void* d_ws, size_t ws_size,
                              hipStream_t stream) {
    const float* beta  = (const float*)d_in[0];
    const float* gamma = (const float*)d_in[1];
    const float* Amat  = (const float*)d_in[2];
    const float* Z_i   = (const float*)d_in[3];
    const float* Z_j   = (const float*)d_in[4];
    const float* Gate  = (const float*)d_in[5];
    const int*   si    = (const int*)d_in[6];
    const int*   sj    = (const int*)d_in[7];
    const int*   sei   = (const int*)d_in[8];
    const int*   sej   = (const int*)d_in[9];

    int n_i = in_sizes[0], n_j = in_sizes[1];
    int m_i = in_sizes[6], m_j = in_sizes[7], E = in_sizes[8];
    int m = m_i + m_j;
    int nTot = n_i + n_j;
    int nblkA = (m + 31) / 32;

    float* ws = (float*)d_ws;
    float* Mpart  = ws; ws += (size_t)nblkA * 1024;
    float* Spart  = ws; ws += (size_t)nblkA * 32;
    float* Mpart2 = ws; ws += NGRP * 1024;
    float* Spart2 = ws; ws += NGRP * 32;
    float* AZC    = ws; ws += 1024;
    float* slots  = ws; ws += 4096;
    float* normI  = ws; ws += n_i;
    float* normJ  = ws; ws += n_j;
    float* Xi_all = ws; ws += (size_t)n_i * KDIM;
    float* Xj_all = ws; ws += (size_t)n_j * KDIM;

    reduce_M<<<nblkA, dim3(32, 32), 0, stream>>>(
        Z_i, Z_j, Gate, si, sj, Mpart, Spart, n_i, n_j, m_i, m);

    reduce2<<<NGRP, 1024, 0, stream>>>(Mpart, Spart, nblkA, Mpart2, Spart2);

    azc_kernel<<<1, dim3(32, 32), 0, stream>>>(Mpart2, Spart2, Amat, AZC);

    xall<<<(nTot + 255) / 256, 256, 0, stream>>>(AZC, Z_i, Z_j, Xi_all, Xj_all,
                                                 normI, normJ, n_i, n_j);

    int nbi = (m_i + 127) / 128, nbj = (m_j + 127) / 128;
    int nedge = (E + 255) / 256;
    int nblkTot = nbi * nbj + nedge;
    pair_edge<<<nblkTot, 256, 0, stream>>>(
        Xi_all, Xj_all, normI, normJ, si, sj, sei, sej, beta, gamma,
        m_i, m_j, E, nbi, nbj, slots);

    final_reduce<<<1, 256, 0, stream>>>(slots, nblkTot, (float*)d_out);
}